// Round 1
// baseline (492.938 us; speedup 1.0000x reference)
//
#include <hip/hip_runtime.h>
#include <math.h>

#define D_OUT 16000
#define IN_DIM 2048
#define BATCH 512

// ---------- complex helpers ----------
__device__ __forceinline__ float2 cmul(float2 a, float2 b) {
    return make_float2(a.x * b.x - a.y * b.y, a.x * b.y + a.y * b.x);
}
__device__ __forceinline__ float2 cadd(float2 a, float2 b) { return make_float2(a.x + b.x, a.y + b.y); }
__device__ __forceinline__ float2 csub(float2 a, float2 b) { return make_float2(a.x - b.x, a.y - b.y); }

// ---------------------------------------------------------------------------
// Kernel 1: extract count-sketch structure. Each row of sketch[2048][16000]
// has exactly one nonzero (+-1). Find its column and sign.
// grid = 4096 (2048 rows x 2 sketches), block = 256.
// ---------------------------------------------------------------------------
__global__ void extract_kernel(const float* __restrict__ sk1, const float* __restrict__ sk2,
                               int* __restrict__ h1, float* __restrict__ s1,
                               int* __restrict__ h2, float* __restrict__ s2) {
    int row = blockIdx.x & (IN_DIM - 1);
    bool second = blockIdx.x >= IN_DIM;
    const float* sk = second ? sk2 : sk1;
    int* h = second ? h2 : h1;
    float* s = second ? s2 : s1;
    const float4* base = (const float4*)(sk + (size_t)row * D_OUT);
    for (int j = threadIdx.x; j < D_OUT / 4; j += 256) {
        float4 v = base[j];
        if (v.x != 0.f) { h[row] = 4 * j + 0; s[row] = v.x; }
        if (v.y != 0.f) { h[row] = 4 * j + 1; s[row] = v.y; }
        if (v.z != 0.f) { h[row] = 4 * j + 2; s[row] = v.z; }
        if (v.w != 0.f) { h[row] = 4 * j + 3; s[row] = v.w; }
    }
}

// ---------------------------------------------------------------------------
// Kernel 2: per-batch-row compact bilinear pooling.
// z = p1 + i*p2 built by scatter into LDS; FFT_16000 (125x128 Cooley-Tukey);
// cross-spectrum G = F1*F2 (Hermitian separation); unnormalized IFFT;
// signed sqrt; write ss; atomic column sum-of-squares.
// grid = 512, block = 1024, LDS = (16000+125+64) float2 = 129512 B.
// ---------------------------------------------------------------------------
#define T2 1024

// 125-point FFTs over stride-128 "columns" (128 of them), in place.
// Column element j lives at z[n2 + 128*j]. 3 radix-5 DIT stages after
// base-5 digit reversal (3-digit reversal is an involution -> in-place swap).
__device__ void fft125_cols(float2* z, const float2* w125, bool inv) {
    for (int idx = threadIdx.x; idx < 16000; idx += T2) {
        int n2 = idx & 127, i = idx >> 7;       // i in [0,125)
        int d0 = i % 5, d1 = (i / 5) % 5, d2 = i / 25;
        int r = d0 * 25 + d1 * 5 + d2;
        if (r > i) {
            float2 a = z[n2 + (i << 7)];
            z[n2 + (i << 7)] = z[n2 + (r << 7)];
            z[n2 + (r << 7)] = a;
        }
    }
    __syncthreads();
    for (int len = 5; len <= 125; len *= 5) {
        int half = len / 5;
        int step = 125 / len;                   // W_len = W_125^step
        for (int w = threadIdx.x; w < 128 * 25; w += T2) {
            int n2 = w & 127, j = w >> 7;       // j in [0,25)
            int g = j / half, q = j - g * half;
            int base = g * len + q;
            float2 b[5];
#pragma unroll
            for (int t = 0; t < 5; t++) {
                float2 v = z[n2 + ((base + t * half) << 7)];
                float2 tw = w125[q * t * step]; // index <= 96 < 125
                if (inv) tw.y = -tw.y;
                b[t] = cmul(v, tw);
            }
#pragma unroll
            for (int u = 0; u < 5; u++) {
                float2 acc = b[0];
#pragma unroll
                for (int t = 1; t < 5; t++) {
                    int e = (u * t) % 5;
                    float2 wv = w125[25 * e];   // omega_5^e
                    if (inv) wv.y = -wv.y;
                    acc = cadd(acc, cmul(b[t], wv));
                }
                z[n2 + ((base + u * half) << 7)] = acc;
            }
        }
        __syncthreads();
    }
}

// 128-point FFTs over contiguous "rows" (125 of them), in place.
// 7 radix-2 DIT stages after 7-bit reversal (involution).
__device__ void fft128_rows(float2* z, const float2* w128, bool inv) {
    for (int idx = threadIdx.x; idx < 16000; idx += T2) {
        int i = idx & 127, row = idx >> 7;      // row in [0,125)
        int r = __brev((unsigned)i) >> 25;      // 7-bit reversal
        if ((int)r > i) {
            float2 a = z[(row << 7) + i];
            z[(row << 7) + i] = z[(row << 7) + r];
            z[(row << 7) + r] = a;
        }
    }
    __syncthreads();
    for (int len = 2; len <= 128; len <<= 1) {
        int half = len >> 1;
        int tstep = 128 / len;                  // W_len = W_128^tstep
        for (int w = threadIdx.x; w < 125 * 64; w += T2) {
            int j = w & 63, row = w >> 6;
            int g = j / half, q = j - g * half;
            int i0 = (row << 7) + g * len + q;
            float2 a = z[i0], b = z[i0 + half];
            float2 tw = w128[q * tstep];        // index < 64
            if (inv) tw.y = -tw.y;
            b = cmul(b, tw);
            z[i0] = cadd(a, b);
            z[i0 + half] = csub(a, b);
        }
        __syncthreads();
    }
}

// Twiddle between the two sub-FFT levels: position p = 128*k1 + n2 gets
// W_16000^{n2*k1} (conj for inverse). n2*k1 <= 127*124 < 16000, no mod needed.
__device__ void twiddle_pass(float2* z, bool inv) {
    for (int p = threadIdx.x; p < 16000; p += T2) {
        int k1 = p >> 7, n2 = p & 127;
        int m = n2 * k1;
        float s, c;
        sincospif(m * (1.0f / 8000.0f), &s, &c);  // angle = 2*pi*m/16000
        float2 tw = make_float2(c, inv ? s : -s);
        z[p] = cmul(z[p], tw);
    }
    __syncthreads();
}

__global__ void __launch_bounds__(T2, 1) cbp_kernel(
    const float* __restrict__ x1, const float* __restrict__ x2,
    const int* __restrict__ h1, const float* __restrict__ s1,
    const int* __restrict__ h2, const float* __restrict__ s2,
    float* __restrict__ out, float* __restrict__ colsum) {
    __shared__ float2 smem[16000 + 125 + 64];
    float2* z = smem;
    float2* w125 = smem + 16000;
    float2* w128 = w125 + 125;
    const int tid = threadIdx.x;
    const int b = blockIdx.x;

    // twiddle tables (forward sign e^{-2*pi*i*t/len})
    for (int t = tid; t < 125; t += T2) {
        float s, c;
        sincospif(t * (2.0f / 125.0f), &s, &c);
        w125[t] = make_float2(c, -s);
    }
    for (int j = tid; j < 64; j += T2) {
        float s, c;
        sincospif(j * (1.0f / 64.0f), &s, &c);
        w128[j] = make_float2(c, -s);
    }
    for (int i = tid; i < 16000; i += T2) z[i] = make_float2(0.f, 0.f);
    __syncthreads();

    // scatter: z.re = p1 = count-sketch(x1), z.im = p2 = count-sketch(x2)
    const float* x1r = x1 + (size_t)b * IN_DIM;
    const float* x2r = x2 + (size_t)b * IN_DIM;
    float* zf = (float*)z;
    for (int i = tid; i < IN_DIM; i += T2) {
        atomicAdd(&zf[2 * h1[i]], x1r[i] * s1[i]);
        atomicAdd(&zf[2 * h2[i] + 1], x2r[i] * s2[i]);
    }
    __syncthreads();

    // forward FFT: cols(125) -> twiddle -> rows(128).
    // Result layout: position 128*k1 + k2 holds frequency k = k1 + 125*k2.
    fft125_cols(z, w125, false);
    twiddle_pass(z, false);
    fft128_rows(z, w128, false);

    // cross-spectrum: F1 = (Z[k] + conj Z[N-k])/2, F2 = -i(Z[k] - conj Z[N-k])/2,
    // G = F1*F2, G[N-k] = conj G[k].
    for (int k = tid; k <= 8000; k += T2) {
        int k1 = k % 125, k2 = k / 125;
        int p = (k1 << 7) + k2;
        int km = (k == 0) ? 0 : 16000 - k;
        int k1m = km % 125, k2m = km / 125;
        int pm = (k1m << 7) + k2m;
        float2 Zk = z[p], Zm = z[pm];
        float2 F1 = make_float2(0.5f * (Zk.x + Zm.x), 0.5f * (Zk.y - Zm.y));
        float2 F2 = make_float2(0.5f * (Zk.y + Zm.y), -0.5f * (Zk.x - Zm.x));
        float2 G = cmul(F1, F2);
        z[p] = G;
        z[pm] = make_float2(G.x, -G.y);
    }
    __syncthreads();

    // inverse (unnormalized; reference's irfft * D cancels the 1/D):
    // rows(128,conj) -> twiddle(conj) -> cols(125,conj). Output natural order.
    fft128_rows(z, w128, true);
    twiddle_pass(z, true);
    fft125_cols(z, w125, true);

    // epilogue: signed sqrt, store, column sum-of-squares
    float* orow = out + (size_t)b * D_OUT;
    for (int n = tid; n < D_OUT; n += T2) {
        float c = z[n].x;
        float ss = (c > 0.f) ? sqrtf(c) : -sqrtf(-c);
        orow[n] = ss;
        atomicAdd(&colsum[n], ss * ss);
    }
}

// ---------------------------------------------------------------------------
// Kernel 3: out[b,n] /= max(sqrt(colsum[n]), 1e-12). float4 vectorized.
// grid = 8000, block = 256 -> 2,048,000 float4 = 8,192,000 floats exactly.
// ---------------------------------------------------------------------------
__global__ void normalize_kernel(float* __restrict__ out, const float* __restrict__ colsum) {
    int idx = blockIdx.x * 256 + threadIdx.x;
    float4* o4 = (float4*)out;
    float4 v = o4[idx];
    int n = (idx * 4) % D_OUT;
    const float4 cs = *(const float4*)(colsum + n);
    v.x /= fmaxf(sqrtf(cs.x), 1e-12f);
    v.y /= fmaxf(sqrtf(cs.y), 1e-12f);
    v.z /= fmaxf(sqrtf(cs.z), 1e-12f);
    v.w /= fmaxf(sqrtf(cs.w), 1e-12f);
    o4[idx] = v;
}

extern "C" void kernel_launch(void* const* d_in, const int* in_sizes, int n_in,
                              void* d_out, int out_size, void* d_ws, size_t ws_size,
                              hipStream_t stream) {
    (void)in_sizes; (void)n_in; (void)out_size; (void)ws_size;
    const float* x1 = (const float*)d_in[0];
    const float* x2 = (const float*)d_in[1];
    const float* sk1 = (const float*)d_in[2];
    const float* sk2 = (const float*)d_in[3];
    float* out = (float*)d_out;

    char* ws = (char*)d_ws;
    int* h1 = (int*)(ws);
    float* s1 = (float*)(ws + 8192);
    int* h2 = (int*)(ws + 16384);
    float* s2 = (float*)(ws + 24576);
    float* colsum = (float*)(ws + 32768);   // 16000 floats

    hipMemsetAsync(colsum, 0, D_OUT * sizeof(float), stream);
    extract_kernel<<<2 * IN_DIM, 256, 0, stream>>>(sk1, sk2, h1, s1, h2, s2);
    cbp_kernel<<<BATCH, T2, 0, stream>>>(x1, x2, h1, s1, h2, s2, out, colsum);
    normalize_kernel<<<8000, 256, 0, stream>>>(out, colsum);
}

// Round 2
// 456.061 us; speedup vs baseline: 1.0809x; 1.0809x over previous
//
#include <hip/hip_runtime.h>
#include <math.h>

#define D_OUT 16000
#define IN_DIM 2048
#define BATCH 512
#define T2 1024
#define PAD 129   // float2 row stride: 258 banks == 2 mod 32 -> 2-way (free) cross-row access

// ---------- complex helpers ----------
__device__ __forceinline__ float2 cmul(float2 a, float2 b) {
    return make_float2(a.x * b.x - a.y * b.y, a.x * b.y + a.y * b.x);
}
__device__ __forceinline__ float2 cadd(float2 a, float2 b) { return make_float2(a.x + b.x, a.y + b.y); }
__device__ __forceinline__ float2 csub(float2 a, float2 b) { return make_float2(a.x - b.x, a.y - b.y); }

// physical LDS index for logical (j in [0,125), i in [0,128))
__device__ __forceinline__ int PZ(int j, int i) { return j * PAD + i; }

// W_16000^m, conj for inverse. m <= 15748 (exact in fp32).
__device__ __forceinline__ float2 bigtw(int m, bool inv) {
    float s, c;
    sincospif((float)m * (1.0f / 8000.0f), &s, &c);
    return make_float2(c, inv ? s : -s);
}

// ---------------------------------------------------------------------------
// Kernel 1: extract count-sketch structure (one signed nonzero per row).
// ---------------------------------------------------------------------------
__global__ void extract_kernel(const float* __restrict__ sk1, const float* __restrict__ sk2,
                               int* __restrict__ h1, float* __restrict__ s1,
                               int* __restrict__ h2, float* __restrict__ s2) {
    int row = blockIdx.x & (IN_DIM - 1);
    bool second = blockIdx.x >= IN_DIM;
    const float* sk = second ? sk2 : sk1;
    int* h = second ? h2 : h1;
    float* s = second ? s2 : s1;
    const float4* base = (const float4*)(sk + (size_t)row * D_OUT);
    for (int j = threadIdx.x; j < D_OUT / 4; j += 256) {
        float4 v = base[j];
        if (v.x != 0.f) { h[row] = 4 * j + 0; s[row] = v.x; }
        if (v.y != 0.f) { h[row] = 4 * j + 1; s[row] = v.y; }
        if (v.z != 0.f) { h[row] = 4 * j + 2; s[row] = v.z; }
        if (v.w != 0.f) { h[row] = 4 * j + 3; s[row] = v.w; }
    }
}

// ---------------------------------------------------------------------------
// 125-point FFTs along the j-dim (128 columns). Digit-reversal first
// (involution); optional fold of the big twiddle (inverse direction only).
// ---------------------------------------------------------------------------
__device__ void fft125_cols(float2* z, const float2* w125, bool inv, bool twiddle) {
    for (int idx = threadIdx.x; idx < 16000; idx += T2) {
        int n2 = idx & 127, i = idx >> 7;        // i in [0,125)
        int d0 = i % 5, d1 = (i / 5) % 5, d2 = i / 25;
        int r = d0 * 25 + d1 * 5 + d2;
        if (r >= i) {
            float2 a = z[PZ(i, n2)];
            float2 b = z[PZ(r, n2)];
            if (twiddle) {
                a = cmul(a, bigtw(n2 * i, inv));
                b = cmul(b, bigtw(n2 * r, inv));
            }
            if (r > i) { z[PZ(i, n2)] = b; z[PZ(r, n2)] = a; }
            else if (twiddle) { z[PZ(i, n2)] = a; }
        }
    }
    __syncthreads();
#pragma unroll
    for (int len = 5; len <= 125; len *= 5) {
        const int half = len / 5;
        const int step = 125 / len;
        for (int w = threadIdx.x; w < 128 * 25; w += T2) {
            int n2 = w & 127, j5 = w >> 7;       // j5 in [0,25)
            int g = j5 / half, q = j5 - g * half;
            int base = g * len + q;
            float2 b[5];
#pragma unroll
            for (int t = 0; t < 5; t++) {
                float2 v = z[PZ(base + t * half, n2)];
                float2 tw = w125[q * t * step];  // index <= 96
                if (inv) tw.y = -tw.y;
                b[t] = cmul(v, tw);
            }
#pragma unroll
            for (int u = 0; u < 5; u++) {
                float2 acc = b[0];
#pragma unroll
                for (int t = 1; t < 5; t++) {
                    int e = (u * t) % 5;
                    float2 wv = w125[25 * e];
                    if (inv) wv.y = -wv.y;
                    acc = cadd(acc, cmul(b[t], wv));
                }
                z[PZ(base + u * half, n2)] = acc;
            }
        }
        __syncthreads();
    }
}

// ---------------------------------------------------------------------------
// 128-point FFTs along the i-dim (125 rows). Bit-reversal (optionally fused
// with the forward big twiddle), then 3 fused register passes:
//   A: len 2+4 (4 pts), B: len 8+16 (4 pts), C: len 32+64+128 (8 pts).
// Work mapped so consecutive lanes hit consecutive rows (2-way with PAD=129).
// ---------------------------------------------------------------------------
__device__ void fft128_rows(float2* z, const float2* w128, bool inv, bool twiddle) {
    const int tid = threadIdx.x;
    for (int idx = tid; idx < 16000; idx += T2) {
        int i = idx / 125, j = idx - i * 125;    // i in [0,128), j in [0,125)
        int r = __brev((unsigned)i) >> 25;
        if ((int)r >= i) {
            float2 a = z[PZ(j, i)];
            float2 b = z[PZ(j, r)];
            if (twiddle) {
                a = cmul(a, bigtw(i * j, inv));
                b = cmul(b, bigtw((int)r * j, inv));
            }
            if ((int)r > i) { z[PZ(j, i)] = b; z[PZ(j, r)] = a; }
            else if (twiddle) { z[PZ(j, i)] = a; }
        }
    }
    __syncthreads();

    // Pass A: fused len=2,4. 32 items/row.
    for (int idx = tid; idx < 4000; idx += T2) {
        int g = idx / 125, j = idx - g * 125;
        int p = PZ(j, 4 * g);
        float2 x0 = z[p], x1 = z[p + 1], x2 = z[p + 2], x3 = z[p + 3];
        float2 a0 = cadd(x0, x1), a1 = csub(x0, x1);
        float2 a2 = cadd(x2, x3), a3 = csub(x2, x3);
        float2 w3 = inv ? make_float2(-a3.y, a3.x) : make_float2(a3.y, -a3.x); // (+-i)*a3
        z[p]     = cadd(a0, a2);
        z[p + 1] = cadd(a1, w3);
        z[p + 2] = csub(a0, a2);
        z[p + 3] = csub(a1, w3);
    }
    __syncthreads();

    // Pass B: fused len=8,16. items: (g in [0,8), q in [0,4)) x 125 rows.
    for (int idx = tid; idx < 4000; idx += T2) {
        int m = idx / 125, j = idx - m * 125;
        int q = m & 3, g = m >> 2;
        int p = PZ(j, 16 * g + q);
        float2 xa = z[p], xb = z[p + 4], xc = z[p + 8], xd = z[p + 12];
        float2 w8 = w128[q * 16]; if (inv) w8.y = -w8.y;
        float2 t = cmul(w8, xb);
        float2 a = cadd(xa, t), b = csub(xa, t);
        t = cmul(w8, xd);
        float2 c = cadd(xc, t), d = csub(xc, t);
        float2 w16a = w128[q * 8];       if (inv) w16a.y = -w16a.y;
        float2 w16b = w128[(q + 4) * 8]; if (inv) w16b.y = -w16b.y;
        t = cmul(w16a, c); z[p] = cadd(a, t);     z[p + 8]  = csub(a, t);
        t = cmul(w16b, d); z[p + 4] = cadd(b, t); z[p + 12] = csub(b, t);
    }
    __syncthreads();

    // Pass C: fused len=32,64,128. items: q in [0,16) x 125 rows, 8 pts each.
    for (int idx = tid; idx < 2000; idx += T2) {
        int q = idx / 125, j = idx - q * 125;
        int p0 = PZ(j, q);
        float2 x[8];
#pragma unroll
        for (int t = 0; t < 8; t++) x[t] = z[p0 + 16 * t];
        // len=32: pairs (x[2s], x[2s+1]), w = W_32^q
        float2 w = w128[q * 4]; if (inv) w.y = -w.y;
#pragma unroll
        for (int s = 0; s < 4; s++) {
            float2 t = cmul(w, x[2 * s + 1]);
            x[2 * s + 1] = csub(x[2 * s], t);
            x[2 * s]     = cadd(x[2 * s], t);
        }
        // len=64: pairs (x0,x2),(x4,x6) w=W_64^q ; (x1,x3),(x5,x7) w=W_64^{q+16}
        float2 wA = w128[q * 2];        if (inv) wA.y = -wA.y;
        float2 wB = w128[q * 2 + 32];   if (inv) wB.y = -wB.y;
        {
            float2 t = cmul(wA, x[2]); x[2] = csub(x[0], t); x[0] = cadd(x[0], t);
            t = cmul(wB, x[3]); x[3] = csub(x[1], t); x[1] = cadd(x[1], t);
            t = cmul(wA, x[6]); x[6] = csub(x[4], t); x[4] = cadd(x[4], t);
            t = cmul(wB, x[7]); x[7] = csub(x[5], t); x[5] = cadd(x[5], t);
        }
        // len=128: pairs (x[t], x[t+4]), w = W_128^{q+16t}
#pragma unroll
        for (int t = 0; t < 4; t++) {
            float2 wv = w128[q + 16 * t]; if (inv) wv.y = -wv.y;
            float2 tt = cmul(wv, x[t + 4]);
            x[t + 4] = csub(x[t], tt);
            x[t]     = cadd(x[t], tt);
        }
#pragma unroll
        for (int t = 0; t < 8; t++) z[p0 + 16 * t] = x[t];
    }
    __syncthreads();
}

// ---------------------------------------------------------------------------
// Kernel 2: per-batch-row CBP. LDS = (125*129 + 125 + 64) float2 = 130512 B.
// ---------------------------------------------------------------------------
__global__ void __launch_bounds__(T2, 1) cbp_kernel(
    const float* __restrict__ x1, const float* __restrict__ x2,
    const int* __restrict__ h1, const float* __restrict__ s1,
    const int* __restrict__ h2, const float* __restrict__ s2,
    float* __restrict__ out) {
    __shared__ float2 smem[125 * PAD + 125 + 64];
    float2* z = smem;
    float2* w125 = smem + 125 * PAD;
    float2* w128 = w125 + 125;
    const int tid = threadIdx.x;
    const int b = blockIdx.x;

    for (int t = tid; t < 125; t += T2) {
        float s, c;
        sincospif(t * (2.0f / 125.0f), &s, &c);
        w125[t] = make_float2(c, -s);
    }
    for (int j = tid; j < 64; j += T2) {
        float s, c;
        sincospif(j * (1.0f / 64.0f), &s, &c);
        w128[j] = make_float2(c, -s);
    }
    for (int i = tid; i < 125 * PAD; i += T2) z[i] = make_float2(0.f, 0.f);
    __syncthreads();

    // scatter: z.re = count-sketch(x1), z.im = count-sketch(x2)
    const float* x1r = x1 + (size_t)b * IN_DIM;
    const float* x2r = x2 + (size_t)b * IN_DIM;
    float* zf = (float*)z;
    for (int i = tid; i < IN_DIM; i += T2) {
        int p1 = PZ(h1[i] >> 7, h1[i] & 127);
        int p2 = PZ(h2[i] >> 7, h2[i] & 127);
        atomicAdd(&zf[2 * p1], x1r[i] * s1[i]);
        atomicAdd(&zf[2 * p2 + 1], x2r[i] * s2[i]);
    }
    __syncthreads();

    // forward: cols(125) -> [big twiddle folded] rows(128)
    fft125_cols(z, w125, false, false);
    fft128_rows(z, w128, false, true);

    // cross-spectrum via Hermitian separation; freq k at logical (j=k%125, i=k/125)
    for (int k = tid; k <= 8000; k += T2) {
        int k1 = k % 125, k2 = k / 125;
        int p = PZ(k1, k2);
        int km = (k == 0) ? 0 : 16000 - k;
        int k1m = km % 125, k2m = km / 125;
        int pm = PZ(k1m, k2m);
        float2 Zk = z[p], Zm = z[pm];
        float2 F1 = make_float2(0.5f * (Zk.x + Zm.x), 0.5f * (Zk.y - Zm.y));
        float2 F2 = make_float2(0.5f * (Zk.y + Zm.y), -0.5f * (Zk.x - Zm.x));
        float2 G = cmul(F1, F2);
        z[p] = G;
        z[pm] = make_float2(G.x, -G.y);
    }
    __syncthreads();

    // inverse: rows(128,conj) -> [conj big twiddle folded] cols(125,conj)
    fft128_rows(z, w128, true, false);
    fft125_cols(z, w125, true, true);

    // epilogue: signed sqrt, store (column norms handled by colsum_kernel)
    float* orow = out + (size_t)b * D_OUT;
    for (int n = tid; n < D_OUT; n += T2) {
        float c = z[PZ(n >> 7, n & 127)].x;
        orow[n] = (c > 0.f) ? sqrtf(c) : -sqrtf(-c);
    }
}

// ---------------------------------------------------------------------------
// Kernel 3: column sum of squares. grid=250, block=512; block owns 64 cols.
// ---------------------------------------------------------------------------
__global__ void colsum_kernel(const float* __restrict__ out, float* __restrict__ colsum) {
    __shared__ float sm[512];
    int c = threadIdx.x & 63, r = threadIdx.x >> 6;
    int col = blockIdx.x * 64 + c;
    float acc = 0.f;
    for (int row = r; row < BATCH; row += 8) {
        float v = out[(size_t)row * D_OUT + col];
        acc += v * v;
    }
    sm[threadIdx.x] = acc;
    __syncthreads();
    if (r == 0) {
        float s = sm[c] + sm[c + 64] + sm[c + 128] + sm[c + 192] +
                  sm[c + 256] + sm[c + 320] + sm[c + 384] + sm[c + 448];
        colsum[col] = s;
    }
}

// ---------------------------------------------------------------------------
// Kernel 4: out[b,n] /= max(sqrt(colsum[n]), 1e-12). float4 vectorized.
// ---------------------------------------------------------------------------
__global__ void normalize_kernel(float* __restrict__ out, const float* __restrict__ colsum) {
    int idx = blockIdx.x * 256 + threadIdx.x;
    float4* o4 = (float4*)out;
    float4 v = o4[idx];
    int n = (idx * 4) % D_OUT;
    const float4 cs = *(const float4*)(colsum + n);
    v.x /= fmaxf(sqrtf(cs.x), 1e-12f);
    v.y /= fmaxf(sqrtf(cs.y), 1e-12f);
    v.z /= fmaxf(sqrtf(cs.z), 1e-12f);
    v.w /= fmaxf(sqrtf(cs.w), 1e-12f);
    o4[idx] = v;
}

extern "C" void kernel_launch(void* const* d_in, const int* in_sizes, int n_in,
                              void* d_out, int out_size, void* d_ws, size_t ws_size,
                              hipStream_t stream) {
    (void)in_sizes; (void)n_in; (void)out_size; (void)ws_size;
    const float* x1 = (const float*)d_in[0];
    const float* x2 = (const float*)d_in[1];
    const float* sk1 = (const float*)d_in[2];
    const float* sk2 = (const float*)d_in[3];
    float* out = (float*)d_out;

    char* ws = (char*)d_ws;
    int* h1 = (int*)(ws);
    float* s1 = (float*)(ws + 8192);
    int* h2 = (int*)(ws + 16384);
    float* s2 = (float*)(ws + 24576);
    float* colsum = (float*)(ws + 32768);   // 16000 floats

    extract_kernel<<<2 * IN_DIM, 256, 0, stream>>>(sk1, sk2, h1, s1, h2, s2);
    cbp_kernel<<<BATCH, T2, 0, stream>>>(x1, x2, h1, s1, h2, s2, out);
    colsum_kernel<<<250, 512, 0, stream>>>(out, colsum);
    normalize_kernel<<<8000, 256, 0, stream>>>(out, colsum);
}

// Round 3
// 393.898 us; speedup vs baseline: 1.2514x; 1.1578x over previous
//
#include <hip/hip_runtime.h>
#include <math.h>

#define D_OUT 16000
#define IN_DIM 2048
#define BATCH 512
#define T2 1024
#define PAD 129   // float2 row stride: 258 banks == 2 mod 32 -> cheap cross-row access

// ---------- complex helpers ----------
__device__ __forceinline__ float2 cmul(float2 a, float2 b) {
    return make_float2(a.x * b.x - a.y * b.y, a.x * b.y + a.y * b.x);
}
__device__ __forceinline__ float2 cadd(float2 a, float2 b) { return make_float2(a.x + b.x, a.y + b.y); }
__device__ __forceinline__ float2 csub(float2 a, float2 b) { return make_float2(a.x - b.x, a.y - b.y); }

__device__ __forceinline__ int PZ(int j, int i) { return j * PAD + i; }

template<int INV>
__device__ __forceinline__ float2 ctw(float2 w) { if (INV) w.y = -w.y; return w; }

// floor(m/125) for m in [0, 15748]
__device__ __forceinline__ int div125(int m) { return (int)(((unsigned)m * 33555u) >> 22); }

// W_16000^m (conj if INV): = W_128^{m/125} * W_16000^{m%125}
template<int INV>
__device__ __forceinline__ float2 bigtw(int m, const float2* w128f, const float2* wNf) {
    int a = div125(m);
    int b = m - a * 125;
    float2 r = cmul(w128f[a], wNf[b]);
    if (INV) r.y = -r.y;
    return r;
}

// 5-point DFT core (Winograd-style). Forward: omega = e^{-2pi i/5}; INV: conj.
template<int INV>
__device__ __forceinline__ void dft5(float2& b0, float2& b1, float2& b2, float2& b3, float2& b4) {
    const float C1 = 0.30901699437494742f, S1 = 0.95105651629515357f;
    const float C2 = -0.80901699437494745f, S2 = 0.58778525229247314f;
    float2 t1 = cadd(b1, b4), t2 = csub(b1, b4);
    float2 t3 = cadd(b2, b3), t4 = csub(b2, b3);
    float2 X0 = make_float2(b0.x + t1.x + t3.x, b0.y + t1.y + t3.y);
    float2 m1 = make_float2(b0.x + C1 * t1.x + C2 * t3.x, b0.y + C1 * t1.y + C2 * t3.y);
    float2 m2 = make_float2(b0.x + C2 * t1.x + C1 * t3.x, b0.y + C2 * t1.y + C1 * t3.y);
    float2 n1 = make_float2(S1 * t2.x + S2 * t4.x, S1 * t2.y + S2 * t4.y);
    float2 n2 = make_float2(S2 * t2.x - S1 * t4.x, S2 * t2.y - S1 * t4.y);
    if (!INV) {
        b1 = make_float2(m1.x + n1.y, m1.y - n1.x);
        b4 = make_float2(m1.x - n1.y, m1.y + n1.x);
        b2 = make_float2(m2.x + n2.y, m2.y - n2.x);
        b3 = make_float2(m2.x - n2.y, m2.y + n2.x);
    } else {
        b1 = make_float2(m1.x - n1.y, m1.y + n1.x);
        b4 = make_float2(m1.x + n1.y, m1.y - n1.x);
        b2 = make_float2(m2.x - n2.y, m2.y + n2.x);
        b3 = make_float2(m2.x + n2.y, m2.y - n2.x);
    }
    b0 = X0;
}

// ---------------------------------------------------------------------------
// Kernel 1: extract count-sketch (one signed +-1 nonzero per row), branch-free:
// h = sum j*|v| (exact: j < 2^24), s = sum v. Block reduce.
// ---------------------------------------------------------------------------
__global__ void extract_kernel(const float* __restrict__ sk1, const float* __restrict__ sk2,
                               int* __restrict__ h1, float* __restrict__ s1,
                               int* __restrict__ h2, float* __restrict__ s2) {
    int row = blockIdx.x & (IN_DIM - 1);
    bool second = blockIdx.x >= IN_DIM;
    const float* sk = second ? sk2 : sk1;
    const float4* base = (const float4*)(sk + (size_t)row * D_OUT);
    float hacc = 0.f, sacc = 0.f;
    for (int j = threadIdx.x; j < D_OUT / 4; j += 256) {
        float4 v = base[j];
        float j4 = (float)(4 * j);
        hacc += j4 * fabsf(v.x) + (j4 + 1.f) * fabsf(v.y) +
                (j4 + 2.f) * fabsf(v.z) + (j4 + 3.f) * fabsf(v.w);
        sacc += v.x + v.y + v.z + v.w;
    }
    for (int off = 32; off; off >>= 1) {
        hacc += __shfl_down(hacc, off);
        sacc += __shfl_down(sacc, off);
    }
    __shared__ float sh[8];
    int lane = threadIdx.x & 63, wv = threadIdx.x >> 6;
    if (lane == 0) { sh[wv] = hacc; sh[wv + 4] = sacc; }
    __syncthreads();
    if (threadIdx.x == 0) {
        float h = sh[0] + sh[1] + sh[2] + sh[3];
        float s = sh[4] + sh[5] + sh[6] + sh[7];
        int* hh = second ? h2 : h1;
        float* ss = second ? s2 : s1;
        hh[row] = (int)(h + 0.5f);
        ss[row] = s;
    }
}

// ---------------------------------------------------------------------------
// Kernel 2: per-batch-row CBP.
// LDS: z[125*129] + w125[125] + w128f[128] + wNf[125] = 132024 B.
// Layout: logical (j in [0,125) = n1/k1 dim, i in [0,128) = n2/k2 dim).
// ---------------------------------------------------------------------------
__global__ void __launch_bounds__(T2, 1) cbp_kernel(
    const float* __restrict__ x1, const float* __restrict__ x2,
    const int* __restrict__ h1, const float* __restrict__ s1,
    const int* __restrict__ h2, const float* __restrict__ s2,
    float* __restrict__ out) {
    __shared__ float2 smem[125 * PAD + 125 + 128 + 125];
    float2* z = smem;
    float2* w125 = smem + 125 * PAD;
    float2* w128f = w125 + 125;
    float2* wNf = w128f + 128;
    const int tid = threadIdx.x;
    const int b = blockIdx.x;

    // tables + zero z
    for (int t = tid; t < 125; t += T2) {
        float s, c;
        sincospif(t * (2.0f / 125.0f), &s, &c);
        w125[t] = make_float2(c, -s);
        sincospif(t * (1.0f / 8000.0f), &s, &c);
        wNf[t] = make_float2(c, -s);
    }
    for (int a = tid; a < 128; a += T2) {
        float s, c;
        sincospif(a * (1.0f / 64.0f), &s, &c);
        w128f[a] = make_float2(c, -s);
    }
    for (int i = tid; i < 125 * PAD; i += T2) z[i] = make_float2(0.f, 0.f);
    __syncthreads();

    // scatter with base-5 digit-reversed j (folds the fwd-col DIT reversal)
    const float* x1r = x1 + (size_t)b * IN_DIM;
    const float* x2r = x2 + (size_t)b * IN_DIM;
    float* zf = (float*)z;
    for (int i = tid; i < IN_DIM; i += T2) {
        int n1 = h1[i] >> 7, n2 = h1[i] & 127;
        int jr = 25 * (n1 % 5) + 5 * ((n1 / 5) % 5) + n1 / 25;
        atomicAdd(&zf[2 * PZ(jr, n2)], x1r[i] * s1[i]);
        n1 = h2[i] >> 7; n2 = h2[i] & 127;
        jr = 25 * (n1 % 5) + 5 * ((n1 / 5) % 5) + n1 / 25;
        atomicAdd(&zf[2 * PZ(jr, n2) + 1], x2r[i] * s2[i]);
    }
    __syncthreads();

    // ---- forward cols: DIT radix-5, stages len=5,25,125 (input digit-reversed)
    // stage len=5 (trivial twiddles)
    for (int w = tid; w < 3200; w += T2) {
        int i = w & 127, g = w >> 7;          // g in [0,25)
        int p = PZ(5 * g, i);
        float2 b0 = z[p], b1 = z[p + PAD], b2 = z[p + 2 * PAD], b3 = z[p + 3 * PAD], b4 = z[p + 4 * PAD];
        dft5<0>(b0, b1, b2, b3, b4);
        z[p] = b0; z[p + PAD] = b1; z[p + 2 * PAD] = b2; z[p + 3 * PAD] = b3; z[p + 4 * PAD] = b4;
    }
    __syncthreads();
    // stage len=25: half=5, step=5
    for (int w = tid; w < 3200; w += T2) {
        int i = w & 127, j5 = w >> 7;
        int g = j5 / 5, q = j5 - 5 * g;
        int p = PZ(g * 25 + q, i);
        float2 b0 = z[p];
        float2 b1 = cmul(z[p + 5 * PAD], w125[q * 5]);
        float2 b2 = cmul(z[p + 10 * PAD], w125[q * 10]);
        float2 b3 = cmul(z[p + 15 * PAD], w125[q * 15]);
        float2 b4 = cmul(z[p + 20 * PAD], w125[q * 20]);
        dft5<0>(b0, b1, b2, b3, b4);
        z[p] = b0; z[p + 5 * PAD] = b1; z[p + 10 * PAD] = b2; z[p + 15 * PAD] = b3; z[p + 20 * PAD] = b4;
    }
    __syncthreads();
    // stage len=125: half=25, step=1; fold big twiddle W_16000^{i*k1} into outputs
    for (int w = tid; w < 3200; w += T2) {
        int i = w & 127, q = w >> 7;          // q in [0,25)
        int p = PZ(q, i);
        float2 b0 = z[p];
        float2 b1 = cmul(z[p + 25 * PAD], w125[q]);
        float2 b2 = cmul(z[p + 50 * PAD], w125[q * 2]);
        float2 b3 = cmul(z[p + 75 * PAD], w125[q * 3]);
        float2 b4 = cmul(z[p + 100 * PAD], w125[q * 4]);
        dft5<0>(b0, b1, b2, b3, b4);
        z[p]             = cmul(b0, bigtw<0>(i * q, w128f, wNf));
        z[p + 25 * PAD]  = cmul(b1, bigtw<0>(i * (q + 25), w128f, wNf));
        z[p + 50 * PAD]  = cmul(b2, bigtw<0>(i * (q + 50), w128f, wNf));
        z[p + 75 * PAD]  = cmul(b3, bigtw<0>(i * (q + 75), w128f, wNf));
        z[p + 100 * PAD] = cmul(b4, bigtw<0>(i * (q + 100), w128f, wNf));
    }
    __syncthreads();

    // ---- forward rows: DIF radix-2, natural input -> bit-reversed output
    // pass Cf: len=128,64,32
    for (int idx = tid; idx < 2000; idx += T2) {
        int q = idx / 125, j = idx - q * 125;
        int p0 = PZ(j, q);
        float2 x[8];
#pragma unroll
        for (int t = 0; t < 8; t++) x[t] = z[p0 + 16 * t];
#pragma unroll
        for (int t = 0; t < 4; t++) {         // len=128: (t, t+4), tw W_128^{q+16t}
            float2 u = cadd(x[t], x[t + 4]);
            float2 d = csub(x[t], x[t + 4]);
            x[t + 4] = cmul(d, w128f[q + 16 * t]);
            x[t] = u;
        }
        {                                     // len=64: tw W_128^{2q}, W_128^{2q+32}
            float2 wA = w128f[2 * q], wB = w128f[2 * q + 32];
            float2 u, d;
            u = cadd(x[0], x[2]); d = csub(x[0], x[2]); x[0] = u; x[2] = cmul(d, wA);
            u = cadd(x[1], x[3]); d = csub(x[1], x[3]); x[1] = u; x[3] = cmul(d, wB);
            u = cadd(x[4], x[6]); d = csub(x[4], x[6]); x[4] = u; x[6] = cmul(d, wA);
            u = cadd(x[5], x[7]); d = csub(x[5], x[7]); x[5] = u; x[7] = cmul(d, wB);
        }
        {                                     // len=32: tw W_128^{4q}
            float2 wC = w128f[4 * q];
#pragma unroll
            for (int s = 0; s < 4; s++) {
                float2 u = cadd(x[2 * s], x[2 * s + 1]);
                float2 d = csub(x[2 * s], x[2 * s + 1]);
                x[2 * s] = u; x[2 * s + 1] = cmul(d, wC);
            }
        }
#pragma unroll
        for (int t = 0; t < 8; t++) z[p0 + 16 * t] = x[t];
    }
    __syncthreads();
    // pass Bf: len=16,8
    for (int idx = tid; idx < 4000; idx += T2) {
        int m = idx / 125, j = idx - m * 125;
        int c = m & 3, g = m >> 2;
        int p = PZ(j, 16 * g + c);
        float2 x0 = z[p], x1 = z[p + 4], x2 = z[p + 8], x3 = z[p + 12];
        float2 wA = w128f[8 * c], wB = w128f[8 * c + 32], wC = w128f[16 * c];
        float2 u, d;
        u = cadd(x0, x2); d = csub(x0, x2); x0 = u; x2 = cmul(d, wA);   // len=16
        u = cadd(x1, x3); d = csub(x1, x3); x1 = u; x3 = cmul(d, wB);
        u = cadd(x0, x1); d = csub(x0, x1); x0 = u; x1 = cmul(d, wC);   // len=8
        u = cadd(x2, x3); d = csub(x2, x3); x2 = u; x3 = cmul(d, wC);
        z[p] = x0; z[p + 4] = x1; z[p + 8] = x2; z[p + 12] = x3;
    }
    __syncthreads();
    // pass Af: len=4,2 (trivial twiddles: 1 and -i)
    for (int idx = tid; idx < 4000; idx += T2) {
        int g = idx / 125, j = idx - g * 125;
        int p = PZ(j, 4 * g);
        float2 x0 = z[p], x1 = z[p + 1], x2 = z[p + 2], x3 = z[p + 3];
        float2 u0 = cadd(x0, x2), v0 = csub(x0, x2);
        float2 u1 = cadd(x1, x3), dd = csub(x1, x3);
        float2 v1 = make_float2(dd.y, -dd.x);   // -i * d (forward)
        z[p]     = cadd(u0, u1);
        z[p + 1] = csub(u0, u1);
        z[p + 2] = cadd(v0, v1);
        z[p + 3] = csub(v0, v1);
    }
    __syncthreads();

    // ---- cross-spectrum (frequency k2 bit-reversed in the i dimension)
    for (int k = tid; k <= 8000; k += T2) {
        int k1 = k % 125, k2 = k / 125;
        int km = (k == 0) ? 0 : 16000 - k;
        int k1m = km % 125, k2m = km / 125;
        int p = PZ(k1, __brev((unsigned)k2) >> 25);
        int pm = PZ(k1m, __brev((unsigned)k2m) >> 25);
        float2 Zk = z[p], Zm = z[pm];
        float2 F1 = make_float2(0.5f * (Zk.x + Zm.x), 0.5f * (Zk.y - Zm.y));
        float2 F2 = make_float2(0.5f * (Zk.y + Zm.y), -0.5f * (Zk.x - Zm.x));
        float2 G = cmul(F1, F2);
        z[p] = G;
        z[pm] = make_float2(G.x, -G.y);
    }
    __syncthreads();

    // ---- inverse rows: DIT radix-2 from bit-reversed input -> natural
    // pass A: len=2,4
    for (int idx = tid; idx < 4000; idx += T2) {
        int g = idx / 125, j = idx - g * 125;
        int p = PZ(j, 4 * g);
        float2 x0 = z[p], x1 = z[p + 1], x2 = z[p + 2], x3 = z[p + 3];
        float2 a0 = cadd(x0, x1), a1 = csub(x0, x1);
        float2 a2 = cadd(x2, x3), a3 = csub(x2, x3);
        float2 w3 = make_float2(-a3.y, a3.x);   // +i * a3 (inverse)
        z[p]     = cadd(a0, a2);
        z[p + 1] = cadd(a1, w3);
        z[p + 2] = csub(a0, a2);
        z[p + 3] = csub(a1, w3);
    }
    __syncthreads();
    // pass B: len=8,16 (conj twiddles)
    for (int idx = tid; idx < 4000; idx += T2) {
        int m = idx / 125, j = idx - m * 125;
        int q = m & 3, g = m >> 2;
        int p = PZ(j, 16 * g + q);
        float2 xa = z[p], xb = z[p + 4], xc = z[p + 8], xd = z[p + 12];
        float2 w8 = ctw<1>(w128f[q * 16]);
        float2 t = cmul(w8, xb);
        float2 a = cadd(xa, t), bb = csub(xa, t);
        t = cmul(w8, xd);
        float2 c = cadd(xc, t), d = csub(xc, t);
        float2 w16a = ctw<1>(w128f[q * 8]);
        float2 w16b = ctw<1>(w128f[(q + 4) * 8]);
        t = cmul(w16a, c); z[p] = cadd(a, t);      z[p + 8]  = csub(a, t);
        t = cmul(w16b, d); z[p + 4] = cadd(bb, t); z[p + 12] = csub(bb, t);
    }
    __syncthreads();
    // pass C: len=32,64,128 (conj twiddles) + fold conj big twiddle on outputs
    for (int idx = tid; idx < 2000; idx += T2) {
        int q = idx / 125, j = idx - q * 125;
        int p0 = PZ(j, q);
        float2 x[8];
#pragma unroll
        for (int t = 0; t < 8; t++) x[t] = z[p0 + 16 * t];
        float2 w = ctw<1>(w128f[q * 4]);
#pragma unroll
        for (int s = 0; s < 4; s++) {           // len=32
            float2 t = cmul(w, x[2 * s + 1]);
            x[2 * s + 1] = csub(x[2 * s], t);
            x[2 * s]     = cadd(x[2 * s], t);
        }
        float2 wA = ctw<1>(w128f[q * 2]);
        float2 wB = ctw<1>(w128f[q * 2 + 32]);
        {                                       // len=64
            float2 t = cmul(wA, x[2]); x[2] = csub(x[0], t); x[0] = cadd(x[0], t);
            t = cmul(wB, x[3]); x[3] = csub(x[1], t); x[1] = cadd(x[1], t);
            t = cmul(wA, x[6]); x[6] = csub(x[4], t); x[4] = cadd(x[4], t);
            t = cmul(wB, x[7]); x[7] = csub(x[5], t); x[5] = cadd(x[5], t);
        }
#pragma unroll
        for (int t = 0; t < 4; t++) {           // len=128
            float2 wv = ctw<1>(w128f[q + 16 * t]);
            float2 tt = cmul(wv, x[t + 4]);
            x[t + 4] = csub(x[t], tt);
            x[t]     = cadd(x[t], tt);
        }
#pragma unroll
        for (int t = 0; t < 8; t++)
            z[p0 + 16 * t] = cmul(x[t], bigtw<1>((q + 16 * t) * j, w128f, wNf));
    }
    __syncthreads();

    // ---- inverse cols: DIF radix-5 (conj), natural input; output digit-reversal
    // absorbed into the final store index. Stage L=125: inputs stride 25.
    for (int w = tid; w < 3200; w += T2) {
        int i = w & 127, q = w >> 7;            // q in [0,25)
        int p = PZ(q, i);
        float2 b0 = z[p], b1 = z[p + 25 * PAD], b2 = z[p + 50 * PAD],
               b3 = z[p + 75 * PAD], b4 = z[p + 100 * PAD];
        dft5<1>(b0, b1, b2, b3, b4);
        z[p]             = b0;
        z[p + 25 * PAD]  = cmul(b1, ctw<1>(w125[q]));
        z[p + 50 * PAD]  = cmul(b2, ctw<1>(w125[2 * q]));
        z[p + 75 * PAD]  = cmul(b3, ctw<1>(w125[3 * q]));
        z[p + 100 * PAD] = cmul(b4, ctw<1>(w125[4 * q]));
    }
    __syncthreads();
    // Stage L=25: blocks of 25, inputs stride 5.
    for (int w = tid; w < 3200; w += T2) {
        int i = w & 127, j5 = w >> 7;
        int u1 = j5 / 5, q2 = j5 - 5 * u1;
        int p = PZ(25 * u1 + q2, i);
        float2 b0 = z[p], b1 = z[p + 5 * PAD], b2 = z[p + 10 * PAD],
               b3 = z[p + 15 * PAD], b4 = z[p + 20 * PAD];
        dft5<1>(b0, b1, b2, b3, b4);
        z[p]            = b0;
        z[p + 5 * PAD]  = cmul(b1, ctw<1>(w125[5 * q2]));
        z[p + 10 * PAD] = cmul(b2, ctw<1>(w125[10 * q2]));
        z[p + 15 * PAD] = cmul(b3, ctw<1>(w125[15 * q2]));
        z[p + 20 * PAD] = cmul(b4, ctw<1>(w125[20 * q2]));
    }
    __syncthreads();
    // Stage L=5 + fused epilogue: signed sqrt -> global. p = 5g+u holds
    // n1 = 25u + 5*(g%5) + g/5.
    float* orow = out + (size_t)b * D_OUT;
    for (int w = tid; w < 3200; w += T2) {
        int i = w & 127, g = w >> 7;
        int p = PZ(5 * g, i);
        float2 b0 = z[p], b1 = z[p + PAD], b2 = z[p + 2 * PAD],
               b3 = z[p + 3 * PAD], b4 = z[p + 4 * PAD];
        dft5<1>(b0, b1, b2, b3, b4);
        int nbase = 5 * (g % 5) + g / 25 + (g / 5) % 5 * 0;  // careful below
        // n1(u) = 25*u + 5*(g%5) + g/5
        int g5 = g % 5, gd = g / 5;
        float re[5] = { b0.x, b1.x, b2.x, b3.x, b4.x };
#pragma unroll
        for (int u = 0; u < 5; u++) {
            int n1 = 25 * u + 5 * g5 + gd;
            float c = re[u];
            orow[n1 * 128 + i] = (c > 0.f) ? sqrtf(c) : -sqrtf(-c);
        }
        (void)nbase;
    }
}

// ---------------------------------------------------------------------------
// Kernel 3: column sum of squares. grid=250, block=512; block owns 64 cols.
// ---------------------------------------------------------------------------
__global__ void colsum_kernel(const float* __restrict__ out, float* __restrict__ colsum) {
    __shared__ float sm[512];
    int c = threadIdx.x & 63, r = threadIdx.x >> 6;
    int col = blockIdx.x * 64 + c;
    float acc = 0.f;
    for (int row = r; row < BATCH; row += 8) {
        float v = out[(size_t)row * D_OUT + col];
        acc += v * v;
    }
    sm[threadIdx.x] = acc;
    __syncthreads();
    if (r == 0) {
        float s = sm[c] + sm[c + 64] + sm[c + 128] + sm[c + 192] +
                  sm[c + 256] + sm[c + 320] + sm[c + 384] + sm[c + 448];
        colsum[col] = s;
    }
}

// ---------------------------------------------------------------------------
// Kernel 4: out[b,n] /= max(sqrt(colsum[n]), 1e-12). float4 vectorized.
// ---------------------------------------------------------------------------
__global__ void normalize_kernel(float* __restrict__ out, const float* __restrict__ colsum) {
    int idx = blockIdx.x * 256 + threadIdx.x;
    float4* o4 = (float4*)out;
    float4 v = o4[idx];
    int n = (idx * 4) % D_OUT;
    const float4 cs = *(const float4*)(colsum + n);
    v.x /= fmaxf(sqrtf(cs.x), 1e-12f);
    v.y /= fmaxf(sqrtf(cs.y), 1e-12f);
    v.z /= fmaxf(sqrtf(cs.z), 1e-12f);
    v.w /= fmaxf(sqrtf(cs.w), 1e-12f);
    o4[idx] = v;
}

extern "C" void kernel_launch(void* const* d_in, const int* in_sizes, int n_in,
                              void* d_out, int out_size, void* d_ws, size_t ws_size,
                              hipStream_t stream) {
    (void)in_sizes; (void)n_in; (void)out_size; (void)ws_size;
    const float* x1 = (const float*)d_in[0];
    const float* x2 = (const float*)d_in[1];
    const float* sk1 = (const float*)d_in[2];
    const float* sk2 = (const float*)d_in[3];
    float* out = (float*)d_out;

    char* ws = (char*)d_ws;
    int* h1 = (int*)(ws);
    float* s1 = (float*)(ws + 8192);
    int* h2 = (int*)(ws + 16384);
    float* s2 = (float*)(ws + 24576);
    float* colsum = (float*)(ws + 32768);   // 16000 floats

    extract_kernel<<<2 * IN_DIM, 256, 0, stream>>>(sk1, sk2, h1, s1, h2, s2);
    cbp_kernel<<<BATCH, T2, 0, stream>>>(x1, x2, h1, s1, h2, s2, out);
    colsum_kernel<<<250, 512, 0, stream>>>(out, colsum);
    normalize_kernel<<<8000, 256, 0, stream>>>(out, colsum);
}

// Round 4
// 384.995 us; speedup vs baseline: 1.2804x; 1.0231x over previous
//
#include <hip/hip_runtime.h>
#include <math.h>

#define D_OUT 16000
#define IN_DIM 2048
#define BATCH 512
#define T2 1024
#define PAD 129   // float2 row stride: 258 banks == 2 mod 32 -> cheap cross-row access

// ---------- complex helpers ----------
__device__ __forceinline__ float2 cmul(float2 a, float2 b) {
    return make_float2(a.x * b.x - a.y * b.y, a.x * b.y + a.y * b.x);
}
__device__ __forceinline__ float2 cadd(float2 a, float2 b) { return make_float2(a.x + b.x, a.y + b.y); }
__device__ __forceinline__ float2 csub(float2 a, float2 b) { return make_float2(a.x - b.x, a.y - b.y); }

__device__ __forceinline__ int PZ(int j, int i) { return j * PAD + i; }

template<int INV>
__device__ __forceinline__ float2 ctw(float2 w) { if (INV) w.y = -w.y; return w; }

// floor(m/125) for m in [0, 15748]
__device__ __forceinline__ int div125(int m) { return (int)(((unsigned)m * 33555u) >> 22); }

// W_16000^m (conj if INV): = W_128^{m/125} * W_16000^{m%125}
template<int INV>
__device__ __forceinline__ float2 bigtw(int m, const float2* w128f, const float2* wNf) {
    int a = div125(m);
    int b = m - a * 125;
    float2 r = cmul(w128f[a], wNf[b]);
    if (INV) r.y = -r.y;
    return r;
}

// 5-point DFT core (Winograd-style). Forward: omega = e^{-2pi i/5}; INV: conj.
template<int INV>
__device__ __forceinline__ void dft5(float2& b0, float2& b1, float2& b2, float2& b3, float2& b4) {
    const float C1 = 0.30901699437494742f, S1 = 0.95105651629515357f;
    const float C2 = -0.80901699437494745f, S2 = 0.58778525229247314f;
    float2 t1 = cadd(b1, b4), t2 = csub(b1, b4);
    float2 t3 = cadd(b2, b3), t4 = csub(b2, b3);
    float2 X0 = make_float2(b0.x + t1.x + t3.x, b0.y + t1.y + t3.y);
    float2 m1 = make_float2(b0.x + C1 * t1.x + C2 * t3.x, b0.y + C1 * t1.y + C2 * t3.y);
    float2 m2 = make_float2(b0.x + C2 * t1.x + C1 * t3.x, b0.y + C2 * t1.y + C1 * t3.y);
    float2 n1 = make_float2(S1 * t2.x + S2 * t4.x, S1 * t2.y + S2 * t4.y);
    float2 n2 = make_float2(S2 * t2.x - S1 * t4.x, S2 * t2.y - S1 * t4.y);
    if (!INV) {
        b1 = make_float2(m1.x + n1.y, m1.y - n1.x);
        b4 = make_float2(m1.x - n1.y, m1.y + n1.x);
        b2 = make_float2(m2.x + n2.y, m2.y - n2.x);
        b3 = make_float2(m2.x - n2.y, m2.y + n2.x);
    } else {
        b1 = make_float2(m1.x - n1.y, m1.y + n1.x);
        b4 = make_float2(m1.x + n1.y, m1.y - n1.x);
        b2 = make_float2(m2.x - n2.y, m2.y + n2.x);
        b3 = make_float2(m2.x + n2.y, m2.y - n2.x);
    }
    b0 = X0;
}

// ---------------------------------------------------------------------------
// Kernel 1: extract count-sketch (one signed +-1 nonzero per row).
// Branch-free: h = sum j*|v| (exact), s = sum v. 8 independent loads in
// flight per thread (latency-bound fix). block=512 (threads 500..511 idle),
// grid = 4096 (2048 rows x 2 sketches). 4000 float4 per row = 8 x 500.
// ---------------------------------------------------------------------------
__global__ void extract_kernel(const float* __restrict__ sk1, const float* __restrict__ sk2,
                               int* __restrict__ h1, float* __restrict__ s1,
                               int* __restrict__ h2, float* __restrict__ s2) {
    int row = blockIdx.x & (IN_DIM - 1);
    bool second = blockIdx.x >= IN_DIM;
    const float* sk = second ? sk2 : sk1;
    const float4* base = (const float4*)(sk + (size_t)row * D_OUT);
    const int t = threadIdx.x;
    float hacc = 0.f, sacc = 0.f;
    if (t < 500) {
        float4 v[8];
#pragma unroll
        for (int c = 0; c < 8; c++) v[c] = base[t + 500 * c];
#pragma unroll
        for (int c = 0; c < 8; c++) {
            float j4 = (float)(4 * (t + 500 * c));
            hacc += j4 * fabsf(v[c].x) + (j4 + 1.f) * fabsf(v[c].y) +
                    (j4 + 2.f) * fabsf(v[c].z) + (j4 + 3.f) * fabsf(v[c].w);
            sacc += v[c].x + v[c].y + v[c].z + v[c].w;
        }
    }
    for (int off = 32; off; off >>= 1) {
        hacc += __shfl_down(hacc, off);
        sacc += __shfl_down(sacc, off);
    }
    __shared__ float sh[16];
    int lane = t & 63, wv = t >> 6;
    if (lane == 0) { sh[wv] = hacc; sh[wv + 8] = sacc; }
    __syncthreads();
    if (t == 0) {
        float h = 0.f, s = 0.f;
#pragma unroll
        for (int w = 0; w < 8; w++) { h += sh[w]; s += sh[w + 8]; }
        int* hh = second ? h2 : h1;
        float* ss = second ? s2 : s1;
        hh[row] = (int)(h + 0.5f);
        ss[row] = s;
    }
}

// ---------------------------------------------------------------------------
// Kernel 2: per-batch-row CBP.
// LDS: z[125*129] + pad + w125[125] + w128f[128] + wNf[125] = 132040 B.
// Logical layout: j in [0,125) (n1/k1 dim), i in [0,128) (n2/k2 dim).
// ---------------------------------------------------------------------------
__global__ void __launch_bounds__(T2, 1) cbp_kernel(
    const float* __restrict__ x1, const float* __restrict__ x2,
    const int* __restrict__ h1, const float* __restrict__ s1,
    const int* __restrict__ h2, const float* __restrict__ s2,
    float* __restrict__ out) {
    __shared__ float2 smem[125 * PAD + 1 + 125 + 128 + 125];
    float2* z = smem;
    float2* w125 = smem + 125 * PAD + 1;
    float2* w128f = w125 + 125;
    float2* wNf = w128f + 128;
    const int tid = threadIdx.x;
    const int b = blockIdx.x;

    // tables + zero z (z zeroed via float4; pad element keeps tables safe)
    for (int t = tid; t < 125; t += T2) {
        float s, c;
        sincospif(t * (2.0f / 125.0f), &s, &c);
        w125[t] = make_float2(c, -s);
        sincospif(t * (1.0f / 8000.0f), &s, &c);
        wNf[t] = make_float2(c, -s);
    }
    for (int a = tid; a < 128; a += T2) {
        float s, c;
        sincospif(a * (1.0f / 64.0f), &s, &c);
        w128f[a] = make_float2(c, -s);
    }
    {
        float4* z4 = (float4*)z;
        for (int i = tid; i < 8063; i += T2) z4[i] = make_float4(0.f, 0.f, 0.f, 0.f);
    }
    __syncthreads();

    // scatter with base-5 digit-reversed j (folds the fwd-col DIT reversal)
    const float* x1r = x1 + (size_t)b * IN_DIM;
    const float* x2r = x2 + (size_t)b * IN_DIM;
    float* zf = (float*)z;
    for (int i = tid; i < IN_DIM; i += T2) {
        int n1 = h1[i] >> 7, n2 = h1[i] & 127;
        int jr = 25 * (n1 % 5) + 5 * ((n1 / 5) % 5) + n1 / 25;
        atomicAdd(&zf[2 * PZ(jr, n2)], x1r[i] * s1[i]);
        n1 = h2[i] >> 7; n2 = h2[i] & 127;
        jr = 25 * (n1 % 5) + 5 * ((n1 / 5) % 5) + n1 / 25;
        atomicAdd(&zf[2 * PZ(jr, n2) + 1], x2r[i] * s2[i]);
    }
    __syncthreads();

    // ---- forward cols: DIT radix-5, stages len=5,25,125 (input digit-reversed)
    for (int w = tid; w < 3200; w += T2) {      // stage len=5 (trivial twiddles)
        int i = w & 127, g = w >> 7;
        int p = PZ(5 * g, i);
        float2 b0 = z[p], b1 = z[p + PAD], b2 = z[p + 2 * PAD], b3 = z[p + 3 * PAD], b4 = z[p + 4 * PAD];
        dft5<0>(b0, b1, b2, b3, b4);
        z[p] = b0; z[p + PAD] = b1; z[p + 2 * PAD] = b2; z[p + 3 * PAD] = b3; z[p + 4 * PAD] = b4;
    }
    __syncthreads();
    for (int w = tid; w < 3200; w += T2) {      // stage len=25
        int i = w & 127, j5 = w >> 7;
        int g = j5 / 5, q = j5 - 5 * g;
        int p = PZ(g * 25 + q, i);
        float2 b0 = z[p];
        float2 b1 = cmul(z[p + 5 * PAD], w125[q * 5]);
        float2 b2 = cmul(z[p + 10 * PAD], w125[q * 10]);
        float2 b3 = cmul(z[p + 15 * PAD], w125[q * 15]);
        float2 b4 = cmul(z[p + 20 * PAD], w125[q * 20]);
        dft5<0>(b0, b1, b2, b3, b4);
        z[p] = b0; z[p + 5 * PAD] = b1; z[p + 10 * PAD] = b2; z[p + 15 * PAD] = b3; z[p + 20 * PAD] = b4;
    }
    __syncthreads();
    for (int w = tid; w < 3200; w += T2) {      // stage len=125 + big twiddle fold
        int i = w & 127, q = w >> 7;
        int p = PZ(q, i);
        float2 b0 = z[p];
        float2 b1 = cmul(z[p + 25 * PAD], w125[q]);
        float2 b2 = cmul(z[p + 50 * PAD], w125[q * 2]);
        float2 b3 = cmul(z[p + 75 * PAD], w125[q * 3]);
        float2 b4 = cmul(z[p + 100 * PAD], w125[q * 4]);
        dft5<0>(b0, b1, b2, b3, b4);
        z[p]             = cmul(b0, bigtw<0>(i * q, w128f, wNf));
        z[p + 25 * PAD]  = cmul(b1, bigtw<0>(i * (q + 25), w128f, wNf));
        z[p + 50 * PAD]  = cmul(b2, bigtw<0>(i * (q + 50), w128f, wNf));
        z[p + 75 * PAD]  = cmul(b3, bigtw<0>(i * (q + 75), w128f, wNf));
        z[p + 100 * PAD] = cmul(b4, bigtw<0>(i * (q + 100), w128f, wNf));
    }
    __syncthreads();

    // ---- forward rows: DIF radix-2, natural -> bit-reversed. 2 passes.
    // Pass R1: stages len=128,64,32,16. Item (q in [0,8), j): i = q+8t, 16 pts.
    if (tid < 1000) {
        int q = tid / 125, j = tid - q * 125;
        int p = PZ(j, q);
        float2 x[16];
#pragma unroll
        for (int t = 0; t < 16; t++) x[t] = z[p + 8 * t];
#pragma unroll
        for (int t = 0; t < 8; t++) {           // len=128: (t, t+8), W_128^{q+8t}
            float2 u = cadd(x[t], x[t + 8]);
            float2 d = csub(x[t], x[t + 8]);
            x[t + 8] = cmul(d, w128f[q + 8 * t]);
            x[t] = u;
        }
#pragma unroll
        for (int h = 0; h < 16; h += 8)         // len=64: (t, t+4), W_128^{2q+16(t&7)}
            for (int t = h; t < h + 4; t++) {
                float2 u = cadd(x[t], x[t + 4]);
                float2 d = csub(x[t], x[t + 4]);
                x[t + 4] = cmul(d, w128f[2 * q + 16 * (t & 7)]);
                x[t] = u;
            }
#pragma unroll
        for (int h = 0; h < 16; h += 4)         // len=32: (t, t+2), W_128^{4q+32(t&3)}
            for (int t = h; t < h + 2; t++) {
                float2 u = cadd(x[t], x[t + 2]);
                float2 d = csub(x[t], x[t + 2]);
                x[t + 2] = cmul(d, w128f[4 * q + 32 * (t & 3)]);
                x[t] = u;
            }
        {
            float2 w16 = w128f[8 * q];          // len=16: (t, t+1), W_16^q
#pragma unroll
            for (int t = 0; t < 16; t += 2) {
                float2 u = cadd(x[t], x[t + 1]);
                float2 d = csub(x[t], x[t + 1]);
                x[t + 1] = cmul(d, w16);
                x[t] = u;
            }
        }
#pragma unroll
        for (int t = 0; t < 16; t++) z[p + 8 * t] = x[t];
    }
    __syncthreads();
    // Pass R2: stages len=8,4,2 on contiguous 8-blocks. Item (g in [0,16), j).
    for (int idx = tid; idx < 2000; idx += T2) {
        int g = idx / 125, j = idx - g * 125;
        int p = PZ(j, 8 * g);
        float2 x[8];
#pragma unroll
        for (int d = 0; d < 8; d++) x[d] = z[p + d];
#pragma unroll
        for (int d = 0; d < 4; d++) {           // len=8: (d, d+4), W_8^d
            float2 u = cadd(x[d], x[d + 4]);
            float2 v = csub(x[d], x[d + 4]);
            x[d + 4] = cmul(v, w128f[16 * d]);
            x[d] = u;
        }
#pragma unroll
        for (int h = 0; h < 8; h += 4) {        // len=4: (h,h+2) w=1; (h+1,h+3) w=-i
            float2 u = cadd(x[h], x[h + 2]);
            float2 v = csub(x[h], x[h + 2]);
            x[h] = u; x[h + 2] = v;
            u = cadd(x[h + 1], x[h + 3]);
            v = csub(x[h + 1], x[h + 3]);
            x[h + 1] = u;
            x[h + 3] = make_float2(v.y, -v.x);  // * (-i)
        }
#pragma unroll
        for (int d = 0; d < 8; d += 2) {        // len=2
            float2 u = cadd(x[d], x[d + 1]);
            float2 v = csub(x[d], x[d + 1]);
            x[d] = u; x[d + 1] = v;
        }
#pragma unroll
        for (int d = 0; d < 8; d++) z[p + d] = x[d];
    }
    __syncthreads();

    // ---- cross-spectrum (frequency k2 bit-reversed in the i dimension)
    for (int k = tid; k <= 8000; k += T2) {
        int k1 = k % 125, k2 = k / 125;
        int km = (k == 0) ? 0 : 16000 - k;
        int k1m = km % 125, k2m = km / 125;
        int p = PZ(k1, __brev((unsigned)k2) >> 25);
        int pm = PZ(k1m, __brev((unsigned)k2m) >> 25);
        float2 Zk = z[p], Zm = z[pm];
        float2 F1 = make_float2(0.5f * (Zk.x + Zm.x), 0.5f * (Zk.y - Zm.y));
        float2 F2 = make_float2(0.5f * (Zk.y + Zm.y), -0.5f * (Zk.x - Zm.x));
        float2 G = cmul(F1, F2);
        z[p] = G;
        z[pm] = make_float2(G.x, -G.y);
    }
    __syncthreads();

    // ---- inverse rows: DIT radix-2 from bit-reversed input. 2 passes.
    // Pass I1: stages len=2,4,8 on contiguous 8-blocks (conj twiddles).
    for (int idx = tid; idx < 2000; idx += T2) {
        int g = idx / 125, j = idx - g * 125;
        int p = PZ(j, 8 * g);
        float2 x[8];
#pragma unroll
        for (int d = 0; d < 8; d++) x[d] = z[p + d];
#pragma unroll
        for (int d = 0; d < 8; d += 2) {        // len=2
            float2 t = x[d + 1];
            x[d + 1] = csub(x[d], t);
            x[d] = cadd(x[d], t);
        }
#pragma unroll
        for (int h = 0; h < 8; h += 4) {        // len=4: (h,h+2) w=1; (h+1,h+3) w=+i
            float2 t = x[h + 2];
            x[h + 2] = csub(x[h], t);
            x[h] = cadd(x[h], t);
            float2 s = x[h + 3];
            t = make_float2(-s.y, s.x);         // * (+i)
            x[h + 3] = csub(x[h + 1], t);
            x[h + 1] = cadd(x[h + 1], t);
        }
#pragma unroll
        for (int d = 0; d < 4; d++) {           // len=8: (d, d+4), conj W_8^d
            float2 t = cmul(ctw<1>(w128f[16 * d]), x[d + 4]);
            x[d + 4] = csub(x[d], t);
            x[d] = cadd(x[d], t);
        }
#pragma unroll
        for (int d = 0; d < 8; d++) z[p + d] = x[d];
    }
    __syncthreads();
    // Pass I2: stages len=16,32,64,128 (conj) + conj big-twiddle fold.
    if (tid < 1000) {
        int q = tid / 125, j = tid - q * 125;
        int p = PZ(j, q);
        float2 x[16];
#pragma unroll
        for (int t = 0; t < 16; t++) x[t] = z[p + 8 * t];
        {
            float2 w16 = ctw<1>(w128f[8 * q]);  // len=16: (t, t+1)
#pragma unroll
            for (int t = 0; t < 16; t += 2) {
                float2 tt = cmul(w16, x[t + 1]);
                x[t + 1] = csub(x[t], tt);
                x[t] = cadd(x[t], tt);
            }
        }
#pragma unroll
        for (int h = 0; h < 16; h += 4)         // len=32: (t, t+2)
            for (int t = h; t < h + 2; t++) {
                float2 w = ctw<1>(w128f[4 * q + 32 * (t & 3)]);
                float2 tt = cmul(w, x[t + 2]);
                x[t + 2] = csub(x[t], tt);
                x[t] = cadd(x[t], tt);
            }
#pragma unroll
        for (int h = 0; h < 16; h += 8)         // len=64: (t, t+4)
            for (int t = h; t < h + 4; t++) {
                float2 w = ctw<1>(w128f[2 * q + 16 * (t & 7)]);
                float2 tt = cmul(w, x[t + 4]);
                x[t + 4] = csub(x[t], tt);
                x[t] = cadd(x[t], tt);
            }
#pragma unroll
        for (int t = 0; t < 8; t++) {           // len=128: (t, t+8)
            float2 w = ctw<1>(w128f[q + 8 * t]);
            float2 tt = cmul(w, x[t + 8]);
            x[t + 8] = csub(x[t], tt);
            x[t] = cadd(x[t], tt);
        }
#pragma unroll
        for (int t = 0; t < 16; t++)
            z[p + 8 * t] = cmul(x[t], bigtw<1>((q + 8 * t) * j, w128f, wNf));
    }
    __syncthreads();

    // ---- inverse cols: DIF radix-5 (conj); output digit-reversal absorbed
    // into the final store index.
    for (int w = tid; w < 3200; w += T2) {      // stage L=125
        int i = w & 127, q = w >> 7;
        int p = PZ(q, i);
        float2 b0 = z[p], b1 = z[p + 25 * PAD], b2 = z[p + 50 * PAD],
               b3 = z[p + 75 * PAD], b4 = z[p + 100 * PAD];
        dft5<1>(b0, b1, b2, b3, b4);
        z[p]             = b0;
        z[p + 25 * PAD]  = cmul(b1, ctw<1>(w125[q]));
        z[p + 50 * PAD]  = cmul(b2, ctw<1>(w125[2 * q]));
        z[p + 75 * PAD]  = cmul(b3, ctw<1>(w125[3 * q]));
        z[p + 100 * PAD] = cmul(b4, ctw<1>(w125[4 * q]));
    }
    __syncthreads();
    for (int w = tid; w < 3200; w += T2) {      // stage L=25
        int i = w & 127, j5 = w >> 7;
        int u1 = j5 / 5, q2 = j5 - 5 * u1;
        int p = PZ(25 * u1 + q2, i);
        float2 b0 = z[p], b1 = z[p + 5 * PAD], b2 = z[p + 10 * PAD],
               b3 = z[p + 15 * PAD], b4 = z[p + 20 * PAD];
        dft5<1>(b0, b1, b2, b3, b4);
        z[p]            = b0;
        z[p + 5 * PAD]  = cmul(b1, ctw<1>(w125[5 * q2]));
        z[p + 10 * PAD] = cmul(b2, ctw<1>(w125[10 * q2]));
        z[p + 15 * PAD] = cmul(b3, ctw<1>(w125[15 * q2]));
        z[p + 20 * PAD] = cmul(b4, ctw<1>(w125[20 * q2]));
    }
    __syncthreads();
    // stage L=5 + fused epilogue: signed sqrt -> global. n1(u) = 25u + 5(g%5) + g/5.
    float* orow = out + (size_t)b * D_OUT;
    for (int w = tid; w < 3200; w += T2) {
        int i = w & 127, g = w >> 7;
        int p = PZ(5 * g, i);
        float2 b0 = z[p], b1 = z[p + PAD], b2 = z[p + 2 * PAD],
               b3 = z[p + 3 * PAD], b4 = z[p + 4 * PAD];
        dft5<1>(b0, b1, b2, b3, b4);
        int g5 = g % 5, gd = g / 5;
        float re[5] = { b0.x, b1.x, b2.x, b3.x, b4.x };
#pragma unroll
        for (int u = 0; u < 5; u++) {
            int n1 = 25 * u + 5 * g5 + gd;
            float c = re[u];
            orow[n1 * 128 + i] = (c > 0.f) ? sqrtf(c) : -sqrtf(-c);
        }
    }
}

// ---------------------------------------------------------------------------
// Kernel 3: column sum of squares. grid=250, block=512; block owns 64 cols.
// ---------------------------------------------------------------------------
__global__ void colsum_kernel(const float* __restrict__ out, float* __restrict__ colsum) {
    __shared__ float sm[512];
    int c = threadIdx.x & 63, r = threadIdx.x >> 6;
    int col = blockIdx.x * 64 + c;
    float acc = 0.f;
    for (int row = r; row < BATCH; row += 8) {
        float v = out[(size_t)row * D_OUT + col];
        acc += v * v;
    }
    sm[threadIdx.x] = acc;
    __syncthreads();
    if (r == 0) {
        float s = sm[c] + sm[c + 64] + sm[c + 128] + sm[c + 192] +
                  sm[c + 256] + sm[c + 320] + sm[c + 384] + sm[c + 448];
        colsum[col] = s;
    }
}

// ---------------------------------------------------------------------------
// Kernel 4: out[b,n] /= max(sqrt(colsum[n]), 1e-12). float4 vectorized.
// ---------------------------------------------------------------------------
__global__ void normalize_kernel(float* __restrict__ out, const float* __restrict__ colsum) {
    int idx = blockIdx.x * 256 + threadIdx.x;
    float4* o4 = (float4*)out;
    float4 v = o4[idx];
    int n = (idx * 4) % D_OUT;
    const float4 cs = *(const float4*)(colsum + n);
    v.x /= fmaxf(sqrtf(cs.x), 1e-12f);
    v.y /= fmaxf(sqrtf(cs.y), 1e-12f);
    v.z /= fmaxf(sqrtf(cs.z), 1e-12f);
    v.w /= fmaxf(sqrtf(cs.w), 1e-12f);
    o4[idx] = v;
}

extern "C" void kernel_launch(void* const* d_in, const int* in_sizes, int n_in,
                              void* d_out, int out_size, void* d_ws, size_t ws_size,
                              hipStream_t stream) {
    (void)in_sizes; (void)n_in; (void)out_size; (void)ws_size;
    const float* x1 = (const float*)d_in[0];
    const float* x2 = (const float*)d_in[1];
    const float* sk1 = (const float*)d_in[2];
    const float* sk2 = (const float*)d_in[3];
    float* out = (float*)d_out;

    char* ws = (char*)d_ws;
    int* h1 = (int*)(ws);
    float* s1 = (float*)(ws + 8192);
    int* h2 = (int*)(ws + 16384);
    float* s2 = (float*)(ws + 24576);
    float* colsum = (float*)(ws + 32768);   // 16000 floats

    extract_kernel<<<2 * IN_DIM, 512, 0, stream>>>(sk1, sk2, h1, s1, h2, s2);
    cbp_kernel<<<BATCH, T2, 0, stream>>>(x1, x2, h1, s1, h2, s2, out);
    colsum_kernel<<<250, 512, 0, stream>>>(out, colsum);
    normalize_kernel<<<8000, 256, 0, stream>>>(out, colsum);
}